// Round 8
// baseline (293.911 us; speedup 1.0000x reference)
//
#include <hip/hip_runtime.h>
#include <math.h>
#include <stdint.h>

typedef unsigned short u16;
typedef unsigned long long u64;
typedef __attribute__((ext_vector_type(8))) short bf16x8;   // 8 bf16 (4 VGPRs)
typedef __attribute__((ext_vector_type(4))) float f32x4;

#define RSQRT1_2F 0.70710678118654752440f
#define MB 1048576UL
#define NBLK 512

// ---------------------------------------------------------------------------
// helpers
// ---------------------------------------------------------------------------
__device__ __forceinline__ u16 rne_bf16(float x) {
  unsigned u = __float_as_uint(x);
  return (u16)((u + 0x7FFFu + ((u >> 16) & 1u)) >> 16);
}
__device__ __forceinline__ float bf16_to_f(u16 h) {
  return __uint_as_float(((unsigned)h) << 16);
}
__device__ __forceinline__ void gload_lds16(const void* g, void* l) {
  __builtin_amdgcn_global_load_lds(
      (__attribute__((address_space(1))) void*)(uintptr_t)g,
      (__attribute__((address_space(3))) void*)(uintptr_t)l, 16, 0, 0);
}
__device__ __forceinline__ float rlane(float v, int sl) {
  return __uint_as_float((unsigned)__builtin_amdgcn_readlane((int)__float_as_uint(v), sl));
}
__device__ __forceinline__ float wave_sum(float v) {
  #pragma unroll
  for (int off = 32; off > 0; off >>= 1) v += __shfl_xor(v, off, 64);
  return v;
}
__device__ __forceinline__ float gelu_exact(float z) {
  return 0.5f * z * (1.0f + erff(z * RSQRT1_2F));
}

// ---------------------------------------------------------------------------
// Manual grid barrier (capture-safe; counters zeroed by hipMemsetAsync).
// 2-level arrivals (32x16 -> 32 -> flag) avoid same-address RMW serialization;
// spin is an agent-scope LOAD (no RMW contention).  Bounded spin (no hangs).
// ---------------------------------------------------------------------------
__device__ __forceinline__ void grid_sync(char* bar, int phase) {
  __syncthreads();
  if (threadIdx.x == 0) {
    unsigned* L1   = (unsigned*)(bar + phase * 4096);          // 32 ctrs, 64B stride
    unsigned* L2   = (unsigned*)(bar + phase * 4096 + 2048);
    unsigned* flag = (unsigned*)(bar + phase * 4096 + 2176);
    __threadfence();
    if (atomicAdd(&L1[(blockIdx.x & 31) * 16], 1u) == 15u) {   // 512/32 = 16 each
      if (atomicAdd(L2, 1u) == 31u) {
        __threadfence();
        atomicExch(flag, 1u);
      }
    }
    int iters = 0;
    while (__hip_atomic_load(flag, __ATOMIC_RELAXED, __HIP_MEMORY_SCOPE_AGENT) == 0u) {
      __builtin_amdgcn_s_sleep(2);
      if (++iters > (1 << 22)) break;   // safety valve: fail, don't hang
    }
    __threadfence();
  }
  __syncthreads();
}

// ---------------------------------------------------------------------------
// W[K][N] f32 -> Wt_hi/lo [N][K] bf16, one 64x64 tile (256 threads).
// ---------------------------------------------------------------------------
template<int K, int N>
__device__ __forceinline__ void wsplit_body(
    const float* __restrict__ W, u16* __restrict__ Whi, u16* __restrict__ Wlo,
    int ntile, int ktile, float* sm /* 64*65 floats */) {
  const int t = threadIdx.x;
  const int n0 = ntile * 64, k0 = ktile * 64;
  #pragma unroll
  for (int q = 0; q < 16; ++q) {
    const int r = q * 4 + (t >> 6);
    sm[r * 65 + (t & 63)] = W[(size_t)(k0 + r) * N + n0 + (t & 63)];
  }
  __syncthreads();
  #pragma unroll
  for (int q = 0; q < 16; ++q) {
    const int nr = q * 4 + (t >> 6);
    const int kc = t & 63;
    const float v = sm[kc * 65 + nr];
    const u16 h = rne_bf16(v);
    const u16 lo = rne_bf16(v - bf16_to_f(h));
    Whi[(size_t)(n0 + nr) * K + k0 + kc] = h;
    Wlo[(size_t)(n0 + nr) * K + k0 + kc] = lo;
  }
  __syncthreads();
}

// ---------------------------------------------------------------------------
// bf16x3 split-MFMA GEMM phase.  BM=128 BN=64 BK=32, double-buffered LDS
// (2x24KB), 2-phase pipeline: stage(t+1) issued before compute(t), one
// barrier/step.  Swizzle col16 ^= ((row>>1)&3)<<4 -> uniform 2 lanes/bank.
// 512 blocks = NX x MY x NZ (split-K).  4 waves 2x2, per-wave 64x32 out.
// ---------------------------------------------------------------------------
template<int NX, int MY, int NZ, int K>
__device__ void gemm_phase(const u16* __restrict__ Ahi, const u16* __restrict__ Alo,
                           const u16* __restrict__ Bhi, const u16* __restrict__ Blo,
                           float* __restrict__ P, char* sb) {
  constexpr int BN = 64, M = 4096;
  constexpr int N = BN * NX;
  constexpr int KCH = K / NZ;
  constexpr int NS = KCH / 32;
  constexpr int BUF = 24576;
  const int t = threadIdx.x, w = t >> 6, l = t & 63, lm = l & 15, lk = l >> 4;
  const int wm = w >> 1, wn = w & 1;
  int bid = (int)blockIdx.x;
  bid = (bid & 7) * 64 + (bid >> 3);            // XCD-chunked bijective remap
  const int z = bid / (NX * MY);
  const int rem = bid % (NX * MY);
  const int my = rem / NX, nx = rem % NX;
  const int m0 = my * 128, n0 = nx * BN, kbase = z * KCH;
  float* __restrict__ Pz = P + (size_t)z * M * N;

  f32x4 acc[4][2];
  #pragma unroll
  for (int m = 0; m < 4; ++m)
    #pragma unroll
    for (int n = 0; n < 2; ++n)
      #pragma unroll
      for (int r = 0; r < 4; ++r) acc[m][n][r] = 0.f;

  const int trow = t >> 2;          // 0..63
  const int tcol = (t & 3) * 16;

  auto STAGE = [&](int bufsel, int k0) {
    char* bb = sb + bufsel * BUF;
    #pragma unroll
    for (int q = 0; q < 2; ++q) {
      const int row = q * 64 + trow;
      const int col = tcol ^ (((row >> 1) & 3) << 4);
      const size_t gb = ((size_t)(m0 + row) * K + k0) * 2 + col;
      gload_lds16((const char*)Ahi + gb, bb + q * 4096 + t * 16);
      gload_lds16((const char*)Alo + gb, bb + 8192 + q * 4096 + t * 16);
    }
    {
      const int row = trow;
      const int col = tcol ^ (((row >> 1) & 3) << 4);
      const size_t gb = ((size_t)(n0 + row) * K + k0) * 2 + col;
      gload_lds16((const char*)Bhi + gb, bb + 16384 + t * 16);
      gload_lds16((const char*)Blo + gb, bb + 20480 + t * 16);
    }
  };
  auto COMPUTE = [&](int bufsel) {
    char* bb = sb + bufsel * BUF;
    bf16x8 ah[4], al[4], bhv[2], blv[2];
    #pragma unroll
    for (int m = 0; m < 4; ++m) {
      const int row = wm * 64 + m * 16 + lm;
      const int col = (lk * 16) ^ (((row >> 1) & 3) << 4);
      ah[m] = *(const bf16x8*)(bb + row * 64 + col);
      al[m] = *(const bf16x8*)(bb + 8192 + row * 64 + col);
    }
    #pragma unroll
    for (int n = 0; n < 2; ++n) {
      const int row = wn * 32 + n * 16 + lm;
      const int col = (lk * 16) ^ (((row >> 1) & 3) << 4);
      bhv[n] = *(const bf16x8*)(bb + 16384 + row * 64 + col);
      blv[n] = *(const bf16x8*)(bb + 20480 + row * 64 + col);
    }
    #pragma unroll
    for (int m = 0; m < 4; ++m)
      #pragma unroll
      for (int n = 0; n < 2; ++n) {
        acc[m][n] = __builtin_amdgcn_mfma_f32_16x16x32_bf16(ah[m], bhv[n], acc[m][n], 0, 0, 0);
        acc[m][n] = __builtin_amdgcn_mfma_f32_16x16x32_bf16(ah[m], blv[n], acc[m][n], 0, 0, 0);
        acc[m][n] = __builtin_amdgcn_mfma_f32_16x16x32_bf16(al[m], bhv[n], acc[m][n], 0, 0, 0);
      }
  };

  STAGE(0, kbase);
  __syncthreads();
  for (int s = 0; s < NS; ++s) {
    if (s + 1 < NS) STAGE((s + 1) & 1, kbase + (s + 1) * 32);
    COMPUTE(s & 1);
    __syncthreads();
  }

  #pragma unroll
  for (int m = 0; m < 4; ++m)
    #pragma unroll
    for (int n = 0; n < 2; ++n) {
      const int col = n0 + wn * 32 + n * 16 + lm;
      #pragma unroll
      for (int r = 0; r < 4; ++r) {
        const int row = m0 + wm * 64 + m * 16 + lk * 4 + r;
        Pz[(size_t)row * N + col] = acc[m][n][r];
      }
    }
}

// ---------------------------------------------------------------------------
// THE mega kernel: all phases, 512 blocks x 256 threads, manual grid syncs.
// ---------------------------------------------------------------------------
#define GFUN(t) ((t) * 64 - (t) * ((t) - 1) / 2)
#define TGATE 0.0498339962f

__global__ __launch_bounds__(256, 2) void mega_kernel(
    const float* __restrict__ pooled, const float* __restrict__ labels,
    const float* __restrict__ ln1_g, const float* __restrict__ ln1_b,
    const float* __restrict__ W1, const float* __restrict__ b1,
    const float* __restrict__ ln2_g, const float* __restrict__ ln2_b,
    const float* __restrict__ W2, const float* __restrict__ b2,
    const float* __restrict__ Wh, const float* __restrict__ bh,
    float* __restrict__ out, char* __restrict__ ws) {
  __shared__ __align__(16) char sb[49152];

  u16*   xhi   = (u16*)(ws);
  u16*   xlo   = (u16*)(ws + 8 * MB);
  u16*   w1thi = (u16*)(ws + 16 * MB);
  u16*   w1tlo = (u16*)(ws + 17 * MB);
  u16*   w2thi = (u16*)(ws + 18 * MB);
  u16*   w2tlo = (u16*)(ws + 18 * MB + 262144);
  float* P1    = (float*)(ws + 19 * MB);          // 2 x 8MB
  u16*   h1nhi = (u16*)(ws + 35 * MB);
  u16*   h1nlo = (u16*)(ws + 39 * MB);
  float* P2    = (float*)(ws + 43 * MB);          // 4 x 4MB
  float* Eo    = (float*)(ws + 59 * MB);
  float* To    = (float*)(ws + 59 * MB + 65536);
  float* Lo    = (float*)(ws + 59 * MB + 131072);
  char*  bar   = ws + 60 * MB;                    // 6 x 4KB (memset-zeroed)
  double* S    = (double*)(ws + 60 * MB + 24576); // mse[256] | ord[64] | cnt u64[64]

  const int t = threadIdx.x, w = t >> 6, l = t & 63;
  const int bid = (int)blockIdx.x;
  const int gw = bid * 4 + w;                     // 0..2047

  // ---------------- P0: LN1 (wave/row) + weight transpose-splits -----------
  {
    #pragma unroll
    for (int pass = 0; pass < 2; ++pass) {
      const int row = gw + pass * 2048;
      const float* xr = pooled + (size_t)row * 1024;
      float v[16];
      #pragma unroll
      for (int q = 0; q < 16; ++q) v[q] = xr[l + q * 64];
      float s = 0.f;
      #pragma unroll
      for (int q = 0; q < 16; ++q) s += v[q];
      s = wave_sum(s);
      const float mu = s * (1.0f / 1024.0f);
      float s2 = 0.f;
      #pragma unroll
      for (int q = 0; q < 16; ++q) { float d = v[q] - mu; s2 = fmaf(d, d, s2); }
      s2 = wave_sum(s2);
      const float rstd = rsqrtf(s2 * (1.0f / 1024.0f) + 1e-5f);
      const size_t base = (size_t)row * 1024;
      #pragma unroll
      for (int q = 0; q < 16; ++q) {
        const int c = l + q * 64;
        const float y = (v[q] - mu) * rstd * ln1_g[c] + ln1_b[c];
        const u16 h = rne_bf16(y);
        xhi[base + c] = h;
        xlo[base + c] = rne_bf16(y - bf16_to_f(h));
      }
    }
    if (bid < 160) {
      __syncthreads();
      float* sm = (float*)sb;
      if (bid < 128) wsplit_body<1024, 512>(W1, w1thi, w1tlo, bid & 7, bid >> 3, sm);
      else           wsplit_body<512, 256>(W2, w2thi, w2tlo, (bid - 128) & 3, (bid - 128) >> 2, sm);
    }
  }
  grid_sync(bar, 0);

  // ---------------- P1: GEMM1 (M4096 N512 K1024, splitK=2) -----------------
  gemm_phase<8, 32, 2, 1024>(xhi, xlo, w1thi, w1tlo, P1, sb);
  grid_sync(bar, 1);

  // ---------------- P2: LN(gelu(P1a+P1b+b1)) -> h1n hi/lo (wave/row) -------
  {
    constexpr size_t ZS1 = (size_t)4096 * 512;
    #pragma unroll
    for (int pass = 0; pass < 2; ++pass) {
      const int row = gw + pass * 2048;
      const size_t base = (size_t)row * 512;
      float v[8];
      #pragma unroll
      for (int q = 0; q < 8; ++q) {
        const int c = l + q * 64;
        float s = b1[c] + P1[base + c] + P1[ZS1 + base + c];
        v[q] = gelu_exact(s);
      }
      float s = 0.f;
      #pragma unroll
      for (int q = 0; q < 8; ++q) s += v[q];
      s = wave_sum(s);
      const float mu = s * (1.0f / 512.0f);
      float s2 = 0.f;
      #pragma unroll
      for (int q = 0; q < 8; ++q) { float d = v[q] - mu; s2 = fmaf(d, d, s2); }
      s2 = wave_sum(s2);
      const float rstd = rsqrtf(s2 * (1.0f / 512.0f) + 1e-5f);
      #pragma unroll
      for (int q = 0; q < 8; ++q) {
        const int c = l + q * 64;
        const float y = (v[q] - mu) * rstd * ln2_g[c] + ln2_b[c];
        const u16 h = rne_bf16(y);
        h1nhi[base + c] = h;
        h1nlo[base + c] = rne_bf16(y - bf16_to_f(h));
      }
    }
  }
  grid_sync(bar, 2);

  // ---------------- P3: GEMM2 (M4096 N256 K512, splitK=4) ------------------
  gemm_phase<4, 32, 4, 512>(h1nhi, h1nlo, w2thi, w2tlo, P2, sb);
  grid_sync(bar, 3);

  // ---------------- P4: head (wave/row): gelu, dot Wh, sigmoid, E/T/L ------
  {
    constexpr size_t ZS2 = (size_t)4096 * 256;
    #pragma unroll
    for (int pass = 0; pass < 2; ++pass) {
      const int row = gw + pass * 2048;
      const size_t base = (size_t)row * 256;
      float a0 = 0.f, a1 = 0.f, a2 = 0.f, a3 = 0.f;
      #pragma unroll
      for (int q = 0; q < 4; ++q) {
        const int k = l + q * 64;
        float s = b2[k];
        #pragma unroll
        for (int z = 0; z < 4; ++z) s += P2[z * ZS2 + base + k];
        const float hv = gelu_exact(s);
        const float4 w4 = *(const float4*)&Wh[k * 4];
        a0 = fmaf(hv, w4.x, a0); a1 = fmaf(hv, w4.y, a1);
        a2 = fmaf(hv, w4.z, a2); a3 = fmaf(hv, w4.w, a3);
      }
      #pragma unroll
      for (int off = 32; off > 0; off >>= 1) {
        a0 += __shfl_down(a0, off, 64);
        a1 += __shfl_down(a1, off, 64);
        a2 += __shfl_down(a2, off, 64);
        a3 += __shfl_down(a3, off, 64);
      }
      if (l == 0) {
        const float z[4] = {a0 + bh[0], a1 + bh[1], a2 + bh[2], a3 + bh[3]};
        float msew = 0.f;
        #pragma unroll
        for (int d = 0; d < 4; ++d) {
          const float p = 1.0f / (1.0f + expf(-z[d]));
          const float lab = labels[row * 4 + d];
          out[1 + row * 4 + d] = p;
          To[row * 4 + d] = 20.0f * p;
          Eo[row * 4 + d] = expf(20.0f * p);
          Lo[row * 4 + d] = expf(20.0f * lab);
          const float df = p - lab;
          msew = fmaf(df, df, msew);
        }
        atomicAdd(&S[row & 255], (double)msew);
      }
    }
  }
  grid_sync(bar, 4);

  // ---------------- P5: pairwise ordering (wave per half 64x64 tile) -------
  {
    double* ordS = S + 256;
    u64*    cntS = (u64*)(S + 320);
    auto PAIR = [&](int u) {
      const int tile = u >> 1;
      const int jbase = (u & 1) * 32;
      int ti = (int)((129.0f - sqrtf(fmaxf(16641.0f - 8.0f * (float)tile, 0.f))) * 0.5f);
      if (ti < 0) ti = 0; if (ti > 63) ti = 63;
      while (ti > 0 && GFUN(ti) > tile) ti--;
      while (ti < 63 && GFUN(ti + 1) <= tile) ti++;
      const int tj = ti + (tile - GFUN(ti));
      const int i = ti * 64 + l, j = tj * 64 + l;
      const float4 e4 = *(const float4*)&Eo[(size_t)i * 4];
      const float4 t4 = *(const float4*)&To[(size_t)i * 4];
      const float4 l4 = *(const float4*)&Lo[(size_t)i * 4];
      const float Ei[4] = {e4.x, e4.y, e4.z, e4.w};
      const float Ti[4] = {t4.x, t4.y, t4.z, t4.w};
      const float Li[4] = {l4.x, l4.y, l4.z, l4.w};
      const float4 ej4 = *(const float4*)&Eo[(size_t)j * 4];
      const float4 tj4 = *(const float4*)&To[(size_t)j * 4];
      const float4 lj4 = *(const float4*)&Lo[(size_t)j * 4];
      const float Ejv[4] = {ej4.x, ej4.y, ej4.z, ej4.w};
      const float Tjv[4] = {tj4.x, tj4.y, tj4.z, tj4.w};
      const float Ljv[4] = {lj4.x, lj4.y, lj4.z, lj4.w};
      const bool diag = (ti == tj);
      float acc[4] = {0.f, 0.f, 0.f, 0.f};
      int cnt = 0;
      #pragma unroll 8
      for (int s = 0; s < 32; ++s) {
        const int jj = jbase + s;
        const bool jok = !diag || (jj > l);
        #pragma unroll
        for (int d = 0; d < 4; ++d) {
          const float Ej = rlane(Ejv[d], jj);
          const float Tj = rlane(Tjv[d], jj);
          const float Lj = rlane(Ljv[d], jj);
          const float logse = __logf(Ei[d] + Ej);
          const float tt = Li[d] * __builtin_amdgcn_rcpf(Li[d] + Lj);
          const float bce = (logse - Tj) - tt * (Ti[d] - Tj);
          const bool m = jok && (fabsf(tt - 0.5f) > TGATE);
          acc[d] += m ? bce : 0.f;
          cnt += m ? 1 : 0;
        }
      }
      float tot = (acc[0] + acc[1]) + (acc[2] + acc[3]);
      #pragma unroll
      for (int off = 32; off > 0; off >>= 1) {
        tot += __shfl_down(tot, off, 64);
        cnt += __shfl_down(cnt, off, 64);
      }
      if (l == 0) {
        const int sl = u & 63;
        atomicAdd(&ordS[sl], (double)tot);
        atomicAdd(&cntS[sl], (u64)cnt);
      }
    };
    PAIR(gw);
    PAIR(gw + 2048);
    if (gw < 64) PAIR(gw + 4096);   // 4160 units total
  }
  grid_sync(bar, 5);

  // ---------------- P6: finalize -------------------------------------------
  if (bid == 0 && w == 0) {
    double m = S[l] + S[l + 64] + S[l + 128] + S[l + 192];
    double o = S[256 + l];
    double c = (double)((u64*)(S + 320))[l];
    #pragma unroll
    for (int off = 32; off > 0; off >>= 1) {
      m += __shfl_down(m, off, 64);
      o += __shfl_down(o, off, 64);
      c += __shfl_down(c, off, 64);
    }
    if (l == 0) {
      const double mse = m / (4096.0 * 4.0);
      const double ord = (c > 0.0) ? (o / c) : 0.0;
      out[0] = (float)(0.5 * mse + 0.5 * ord);
    }
  }
}

// ---------------------------------------------------------------------------
extern "C" void kernel_launch(void* const* d_in, const int* in_sizes, int n_in,
                              void* d_out, int out_size, void* d_ws, size_t ws_size,
                              hipStream_t stream) {
  const float* pooled = (const float*)d_in[0];
  const float* labels = (const float*)d_in[1];
  const float* ln1_g  = (const float*)d_in[2];
  const float* ln1_b  = (const float*)d_in[3];
  const float* W1     = (const float*)d_in[4];
  const float* b1     = (const float*)d_in[5];
  const float* ln2_g  = (const float*)d_in[6];
  const float* ln2_b  = (const float*)d_in[7];
  const float* W2     = (const float*)d_in[8];
  const float* b2     = (const float*)d_in[9];
  const float* Wh     = (const float*)d_in[10];
  const float* bh     = (const float*)d_in[11];
  float* out = (float*)d_out;
  char*  ws  = (char*)d_ws;

  // Zero the barrier counters (6x4KB) + loss slots (3KB) — capture-safe.
  hipMemsetAsync(ws + 60 * MB, 0, 32768, stream);
  mega_kernel<<<NBLK, 256, 0, stream>>>(pooled, labels, ln1_g, ln1_b, W1, b1,
                                        ln2_g, ln2_b, W2, b2, Wh, bh, out, ws);
}

// Round 9
// 213.304 us; speedup vs baseline: 1.3779x; 1.3779x over previous
//
#include <hip/hip_runtime.h>
#include <math.h>
#include <stdint.h>

typedef unsigned short u16;
typedef unsigned long long u64;
typedef __attribute__((ext_vector_type(8))) short bf16x8;   // 8 bf16 (4 VGPRs)
typedef __attribute__((ext_vector_type(4))) float f32x4;

#define RSQRT1_2F 0.70710678118654752440f

// ---------------------------------------------------------------------------
// helpers
// ---------------------------------------------------------------------------
__device__ __forceinline__ u16 rne_bf16(float x) {
  unsigned u = __float_as_uint(x);
  return (u16)((u + 0x7FFFu + ((u >> 16) & 1u)) >> 16);
}
__device__ __forceinline__ float bf16_to_f(u16 h) {
  return __uint_as_float(((unsigned)h) << 16);
}
__device__ __forceinline__ void gload_lds16(const void* g, void* l) {
  __builtin_amdgcn_global_load_lds(
      (__attribute__((address_space(1))) void*)(uintptr_t)g,
      (__attribute__((address_space(3))) void*)(uintptr_t)l, 16, 0, 0);
}
__device__ __forceinline__ float rlane(float v, int sl) {
  return __uint_as_float((unsigned)__builtin_amdgcn_readlane((int)__float_as_uint(v), sl));
}
__device__ __forceinline__ float block_reduce_sum_f(float v, float* smem4) {
  #pragma unroll
  for (int off = 32; off > 0; off >>= 1) v += __shfl_down(v, off, 64);
  const int lane = threadIdx.x & 63;
  const int wid  = threadIdx.x >> 6;
  if (lane == 0) smem4[wid] = v;
  __syncthreads();
  float r = smem4[0] + smem4[1] + smem4[2] + smem4[3];
  __syncthreads();
  return r;
}
__device__ __forceinline__ float gelu_exact(float z) {
  return 0.5f * z * (1.0f + erff(z * RSQRT1_2F));
}

// ---------------------------------------------------------------------------
// prep bodies (proven R7 versions)
// ---------------------------------------------------------------------------
template<int H, int NPT>
__device__ __forceinline__ void ln_split_body(
    const float* __restrict__ x, const float* __restrict__ g,
    const float* __restrict__ b, u16* __restrict__ yhi, u16* __restrict__ ylo,
    int row, float* smem4) {
  const float* xr = x + (size_t)row * H;
  const int tid = threadIdx.x;
  float v[NPT];
  #pragma unroll
  for (int q = 0; q < NPT; ++q) v[q] = xr[tid + q * 256];
  float s = 0.f;
  #pragma unroll
  for (int q = 0; q < NPT; ++q) s += v[q];
  s = block_reduce_sum_f(s, smem4);
  const float mu = s * (1.0f / H);
  float s2 = 0.f;
  #pragma unroll
  for (int q = 0; q < NPT; ++q) { float d = v[q] - mu; s2 = fmaf(d, d, s2); }
  s2 = block_reduce_sum_f(s2, smem4);
  const float rstd = rsqrtf(s2 * (1.0f / H) + 1e-5f);
  #pragma unroll
  for (int q = 0; q < NPT; ++q) {
    const int c = tid + q * 256;
    const float y = (v[q] - mu) * rstd * g[c] + b[c];
    const u16 h = rne_bf16(y);
    const u16 lo = rne_bf16(y - bf16_to_f(h));
    yhi[(size_t)row * H + c] = h;
    ylo[(size_t)row * H + c] = lo;
  }
}

template<int K, int N>
__device__ __forceinline__ void wsplit_body(
    const float* __restrict__ W, u16* __restrict__ Whi, u16* __restrict__ Wlo,
    int ntile, int ktile, float* sm /* 64*65 floats */) {
  const int t = threadIdx.x;
  const int n0 = ntile * 64, k0 = ktile * 64;
  #pragma unroll
  for (int q = 0; q < 16; ++q) {
    const int r = q * 4 + (t >> 6);
    sm[r * 65 + (t & 63)] = W[(size_t)(k0 + r) * N + n0 + (t & 63)];
  }
  __syncthreads();
  #pragma unroll
  for (int q = 0; q < 16; ++q) {
    const int nr = q * 4 + (t >> 6);
    const int kc = t & 63;
    const float v = sm[kc * 65 + nr];
    const u16 h = rne_bf16(v);
    const u16 lo = rne_bf16(v - bf16_to_f(h));
    Whi[(size_t)(n0 + nr) * K + k0 + kc] = h;
    Wlo[(size_t)(n0 + nr) * K + k0 + kc] = lo;
  }
}

// ---------------------------------------------------------------------------
// prep: blocks [0,4096) = LN1 rows; [4096,4224) = W1 tiles; [4224,4256) = W2.
// ---------------------------------------------------------------------------
__global__ __launch_bounds__(256) void prep_kernel(
    const float* __restrict__ pooled, const float* __restrict__ ln1_g,
    const float* __restrict__ ln1_b, const float* __restrict__ W1,
    const float* __restrict__ W2,
    u16* __restrict__ xhi, u16* __restrict__ xlo,
    u16* __restrict__ w1thi, u16* __restrict__ w1tlo,
    u16* __restrict__ w2thi, u16* __restrict__ w2tlo) {
  __shared__ float sm[64 * 65];
  const int bid = blockIdx.x;
  if (bid < 4096) {
    ln_split_body<1024, 4>(pooled, ln1_g, ln1_b, xhi, xlo, bid, sm);
  } else if (bid < 4224) {
    const int idx = bid - 4096;
    wsplit_body<1024, 512>(W1, w1thi, w1tlo, idx & 7, idx >> 3, sm);
  } else {
    const int idx = bid - 4224;
    wsplit_body<512, 256>(W2, w2thi, w2tlo, idx & 3, idx >> 2, sm);
  }
}

// ---------------------------------------------------------------------------
// bf16x3 split-MFMA GEMM, splitK=1, fused bias + exact GELU epilogue.
// Tile BM x 64, BK=32, double-buffered LDS, 2-phase pipeline (stage t+1
// issued before compute t, one barrier/step).  Swizzle col ^= ((row>>1)&3)<<4
// -> even 8 lanes per bank-quad on ds_read_b128 (optimal).  4 waves (2x2).
// Grid flat NX*MY with XCD-chunked bijective remap (nwg % 8 == 0).
// zclr: block 0 zeroes the 96 loss accumulator slots.
// ---------------------------------------------------------------------------
template<int BM, int NX, int MY, int K>
__global__ __launch_bounds__(256) void gemm_gelu_kernel(
    const u16* __restrict__ Ahi, const u16* __restrict__ Alo,
    const u16* __restrict__ Bhi, const u16* __restrict__ Blo,
    const float* __restrict__ bias, float* __restrict__ C, double* zclr) {
  constexpr int N  = NX * 64;
  constexpr int MF = BM / 32;             // M fragments per wave
  constexpr int ABYTES = BM * 64;         // one A half (hi or lo) per buffer
  constexpr int AOFF = 2 * ABYTES;        // B region offset
  constexpr int BUF  = AOFF + 8192;       // + B hi/lo (64 rows x 64 B x 2)
  constexpr int NS   = K / 32;
  __shared__ __align__(16) char sb[2 * BUF];

  if (zclr && blockIdx.x == 0 && threadIdx.x < 32) {
    zclr[threadIdx.x] = 0.0;                    // mse slots
    zclr[32 + threadIdx.x] = 0.0;               // ordering slots
    ((u64*)(zclr + 64))[threadIdx.x] = 0ull;    // count slots
  }

  const int t = threadIdx.x, w = t >> 6, l = t & 63;
  const int lm = l & 15, lk = l >> 4;
  const int wm = w >> 1, wn = w & 1;
  int bid = (int)blockIdx.x;
  bid = (bid & 7) * ((NX * MY) >> 3) + (bid >> 3);   // XCD-chunked remap
  const int my = bid / NX, nx = bid % NX;
  const int m0 = my * BM, n0 = nx * 64;

  f32x4 acc[MF][2];
  #pragma unroll
  for (int m = 0; m < MF; ++m)
    #pragma unroll
    for (int n = 0; n < 2; ++n)
      #pragma unroll
      for (int r = 0; r < 4; ++r) acc[m][n][r] = 0.f;

  auto STAGE = [&](int bufsel, int k0) {
    char* bb = sb + bufsel * BUF;
    if constexpr (BM == 64) {
      const int row = t >> 2, cq = (t & 3) * 16;
      const int col = cq ^ (((row >> 1) & 3) << 4);
      const size_t gb = ((size_t)(m0 + row) * K + k0) * 2 + col;
      gload_lds16((const char*)Ahi + gb, bb + t * 16);
      gload_lds16((const char*)Alo + gb, bb + ABYTES + t * 16);
    } else {  // BM == 32: threads<128 stage hi, >=128 stage lo
      const int half = t >> 7, tt = t & 127;
      const int row = tt >> 2, cq = (tt & 3) * 16;
      const int col = cq ^ (((row >> 1) & 3) << 4);
      const size_t gb = ((size_t)(m0 + row) * K + k0) * 2 + col;
      gload_lds16((const char*)(half ? Alo : Ahi) + gb,
                  bb + half * ABYTES + tt * 16);
    }
    {
      const int row = t >> 2, cq = (t & 3) * 16;
      const int col = cq ^ (((row >> 1) & 3) << 4);
      const size_t gb = ((size_t)(n0 + row) * K + k0) * 2 + col;
      gload_lds16((const char*)Bhi + gb, bb + AOFF + t * 16);
      gload_lds16((const char*)Blo + gb, bb + AOFF + 4096 + t * 16);
    }
  };
  auto COMPUTE = [&](int bufsel) {
    char* bb = sb + bufsel * BUF;
    bf16x8 ah[MF], al[MF], bhv[2], blv[2];
    #pragma unroll
    for (int m = 0; m < MF; ++m) {
      const int row = wm * (BM / 2) + m * 16 + lm;
      const int col = (lk * 16) ^ (((row >> 1) & 3) << 4);
      ah[m] = *(const bf16x8*)(bb + row * 64 + col);
      al[m] = *(const bf16x8*)(bb + ABYTES + row * 64 + col);
    }
    #pragma unroll
    for (int n = 0; n < 2; ++n) {
      const int row = wn * 32 + n * 16 + lm;
      const int col = (lk * 16) ^ (((row >> 1) & 3) << 4);
      bhv[n] = *(const bf16x8*)(bb + AOFF + row * 64 + col);
      blv[n] = *(const bf16x8*)(bb + AOFF + 4096 + row * 64 + col);
    }
    #pragma unroll
    for (int m = 0; m < MF; ++m)
      #pragma unroll
      for (int n = 0; n < 2; ++n) {
        acc[m][n] = __builtin_amdgcn_mfma_f32_16x16x32_bf16(ah[m], bhv[n], acc[m][n], 0, 0, 0);
        acc[m][n] = __builtin_amdgcn_mfma_f32_16x16x32_bf16(ah[m], blv[n], acc[m][n], 0, 0, 0);
        acc[m][n] = __builtin_amdgcn_mfma_f32_16x16x32_bf16(al[m], bhv[n], acc[m][n], 0, 0, 0);
      }
  };

  STAGE(0, 0);
  __syncthreads();
  for (int s = 0; s < NS; ++s) {
    if (s + 1 < NS) STAGE((s + 1) & 1, (s + 1) * 32);
    COMPUTE(s & 1);
    __syncthreads();
  }

  // fused epilogue: bias + exact GELU, fp32 store
  #pragma unroll
  for (int m = 0; m < MF; ++m)
    #pragma unroll
    for (int n = 0; n < 2; ++n) {
      const int col = n0 + wn * 32 + n * 16 + lm;
      const float bv = bias[col];
      #pragma unroll
      for (int r = 0; r < 4; ++r) {
        const int row = m0 + wm * (BM / 2) + m * 16 + lk * 4 + r;
        C[(size_t)row * N + col] = gelu_exact(acc[m][n][r] + bv);
      }
    }
}

// ---------------------------------------------------------------------------
// LN2: plain LayerNorm over h1g (gelu already applied by gemm1 epilogue).
// ---------------------------------------------------------------------------
template<int H, int NPT>
__global__ __launch_bounds__(256) void ln2_kernel(
    const float* __restrict__ x, const float* __restrict__ g,
    const float* __restrict__ b, u16* __restrict__ yhi, u16* __restrict__ ylo) {
  __shared__ float smem4[4];
  ln_split_body<H, NPT>(x, g, b, yhi, ylo, blockIdx.x, smem4);
}

// ---------------------------------------------------------------------------
// Head: h2g already gelu'd; z = h2g @ Wh + bh; p = sigmoid.
// Emits logits, T=20*p, E=exp(20*p), L=exp(20*label), MSE into spread slots.
// ---------------------------------------------------------------------------
__global__ __launch_bounds__(256) void head_kernel(
    const float* __restrict__ h2g, const float* __restrict__ Wh,
    const float* __restrict__ bh, const float* __restrict__ labels,
    float* __restrict__ logits_out, float* __restrict__ To,
    float* __restrict__ Eo, float* __restrict__ Lo,
    double* __restrict__ mse_slots) {
  const int lane = threadIdx.x & 63;
  const int wv   = threadIdx.x >> 6;
  const int row  = blockIdx.x * 4 + wv;
  const size_t base = (size_t)row * 256;
  float a0 = 0.f, a1 = 0.f, a2 = 0.f, a3 = 0.f;
  #pragma unroll
  for (int q = 0; q < 4; ++q) {
    const int k = lane + q * 64;
    const float hv = h2g[base + k];
    const float4 wv4 = *(const float4*)&Wh[k * 4];
    a0 = fmaf(hv, wv4.x, a0); a1 = fmaf(hv, wv4.y, a1);
    a2 = fmaf(hv, wv4.z, a2); a3 = fmaf(hv, wv4.w, a3);
  }
  #pragma unroll
  for (int off = 32; off > 0; off >>= 1) {
    a0 += __shfl_down(a0, off, 64);
    a1 += __shfl_down(a1, off, 64);
    a2 += __shfl_down(a2, off, 64);
    a3 += __shfl_down(a3, off, 64);
  }
  if (lane == 0) {
    const float z[4] = {a0 + bh[0], a1 + bh[1], a2 + bh[2], a3 + bh[3]};
    float msew = 0.f;
    #pragma unroll
    for (int d = 0; d < 4; ++d) {
      const float p = 1.0f / (1.0f + expf(-z[d]));
      const float lab = labels[row * 4 + d];
      logits_out[row * 4 + d] = p;
      To[row * 4 + d] = 20.0f * p;
      Eo[row * 4 + d] = expf(20.0f * p);
      Lo[row * 4 + d] = expf(20.0f * lab);
      const float df = p - lab;
      msew = fmaf(df, df, msew);
    }
    atomicAdd(&mse_slots[row & 31], (double)msew);
  }
}

// ---------------------------------------------------------------------------
// Pairwise ordering loss: one WAVE per QUARTER of a 64x64 upper-triangle tile
// (2080 tiles x 4 = 8320 waves, 2080 blocks).  All data in registers;
// j broadcast via readlane.  No LDS, no barriers.
//   bce = log(Ei+Ej) - Tj - t*(Ti-Tj);  t = Li/(Li+Lj)
//   gate |li-lj|>0.01  <=>  |t-0.5| > sigmoid(0.2)-0.5
// ---------------------------------------------------------------------------
#define GFUN(t) ((t) * 64 - (t) * ((t) - 1) / 2)
#define TGATE 0.0498339962f

__global__ __launch_bounds__(256) void pairwise_kernel(
    const float* __restrict__ To, const float* __restrict__ E,
    const float* __restrict__ L, double* __restrict__ slots) {
  const int lane = threadIdx.x & 63;
  const int wv   = threadIdx.x >> 6;
  const int idx  = blockIdx.x * 4 + wv;     // 0..8319
  const int tile = idx >> 2;
  const int jbase = (idx & 3) * 16;

  int ti = (int)((129.0f - sqrtf(fmaxf(16641.0f - 8.0f * (float)tile, 0.f))) * 0.5f);
  if (ti < 0) ti = 0; if (ti > 63) ti = 63;
  while (ti > 0 && GFUN(ti) > tile) ti--;
  while (ti < 63 && GFUN(ti + 1) <= tile) ti++;
  const int tj = ti + (tile - GFUN(ti));
  const int i = ti * 64 + lane, j = tj * 64 + lane;

  const float4 e4 = *(const float4*)&E[(size_t)i * 4];
  const float4 t4 = *(const float4*)&To[(size_t)i * 4];
  const float4 l4 = *(const float4*)&L[(size_t)i * 4];
  const float Ei[4] = {e4.x, e4.y, e4.z, e4.w};
  const float Ti[4] = {t4.x, t4.y, t4.z, t4.w};
  const float Li[4] = {l4.x, l4.y, l4.z, l4.w};
  const float4 ej4 = *(const float4*)&E[(size_t)j * 4];
  const float4 tj4 = *(const float4*)&To[(size_t)j * 4];
  const float4 lj4 = *(const float4*)&L[(size_t)j * 4];
  const float Ejv[4] = {ej4.x, ej4.y, ej4.z, ej4.w};
  const float Tjv[4] = {tj4.x, tj4.y, tj4.z, tj4.w};
  const float Ljv[4] = {lj4.x, lj4.y, lj4.z, lj4.w};

  const bool diag = (ti == tj);
  float acc[4] = {0.f, 0.f, 0.f, 0.f};
  int cnt = 0;
  #pragma unroll
  for (int s = 0; s < 16; ++s) {
    const int jj = jbase + s;
    const bool jok = !diag || (jj > lane);
    #pragma unroll
    for (int d = 0; d < 4; ++d) {
      const float Ej = rlane(Ejv[d], jj);
      const float Tj = rlane(Tjv[d], jj);
      const float Lj = rlane(Ljv[d], jj);
      const float logse = __logf(Ei[d] + Ej);
      const float tt = Li[d] * __builtin_amdgcn_rcpf(Li[d] + Lj);
      const float bce = (logse - Tj) - tt * (Ti[d] - Tj);
      const bool m = jok && (fabsf(tt - 0.5f) > TGATE);
      acc[d] += m ? bce : 0.f;
      cnt += m ? 1 : 0;
    }
  }

  float tot = (acc[0] + acc[1]) + (acc[2] + acc[3]);
  #pragma unroll
  for (int off = 32; off > 0; off >>= 1) {
    tot += __shfl_down(tot, off, 64);
    cnt += __shfl_down(cnt, off, 64);
  }
  if (lane == 0) {
    const int sl = idx & 31;
    atomicAdd(&slots[32 + sl], (double)tot);
    atomicAdd((u64*)(slots + 64) + sl, (u64)cnt);
  }
}

// ---------------------------------------------------------------------------
// finalize: reduce the 32-slot accumulators, write the scalar loss.
// ---------------------------------------------------------------------------
__global__ void finalize_kernel(const double* __restrict__ slots,
                                float* __restrict__ out) {
  const int l = threadIdx.x;   // 64 threads
  double m = (l < 32) ? slots[l] : 0.0;
  double o = (l < 32) ? slots[32 + l] : 0.0;
  double c = (l < 32) ? (double)((const u64*)(slots + 64))[l] : 0.0;
  #pragma unroll
  for (int off = 32; off > 0; off >>= 1) {
    m += __shfl_down(m, off, 64);
    o += __shfl_down(o, off, 64);
    c += __shfl_down(c, off, 64);
  }
  if (l == 0) {
    const double mse = m / (4096.0 * 4.0);
    const double ord = (c > 0.0) ? (o / c) : 0.0;
    out[0] = (float)(0.5 * mse + 0.5 * ord);
  }
}

// ---------------------------------------------------------------------------
extern "C" void kernel_launch(void* const* d_in, const int* in_sizes, int n_in,
                              void* d_out, int out_size, void* d_ws, size_t ws_size,
                              hipStream_t stream) {
  const float* pooled = (const float*)d_in[0];
  const float* labels = (const float*)d_in[1];
  const float* ln1_g  = (const float*)d_in[2];
  const float* ln1_b  = (const float*)d_in[3];
  const float* W1     = (const float*)d_in[4];
  const float* b1     = (const float*)d_in[5];
  const float* ln2_g  = (const float*)d_in[6];
  const float* ln2_b  = (const float*)d_in[7];
  const float* W2     = (const float*)d_in[8];
  const float* b2     = (const float*)d_in[9];
  const float* Wh     = (const float*)d_in[10];
  const float* bh     = (const float*)d_in[11];
  float* out = (float*)d_out;

  // ws layout (bytes), all regions disjoint, peak ~39.3 MiB:
  //  xhi 8M@0 | xlo 8M@8M | w1thi 1M@16M | w1tlo 1M@17M | w2thi 256K@18M |
  //  w2tlo 256K@18.25M | h1g 8M@19M | h1nhi 4M@27M | h1nlo 4M@31M |
  //  h2g 4M@35M | Eo/To/Lo 64K each @39M.. | slots 768B @39M+192K
  char* ws = (char*)d_ws;
  const size_t MB_ = 1048576;
  u16*   xhi   = (u16*)(ws + 0);
  u16*   xlo   = (u16*)(ws + 8 * MB_);
  u16*   w1thi = (u16*)(ws + 16 * MB_);
  u16*   w1tlo = (u16*)(ws + 17 * MB_);
  u16*   w2thi = (u16*)(ws + 18 * MB_);
  u16*   w2tlo = (u16*)(ws + 18 * MB_ + 262144);
  float* h1g   = (float*)(ws + 19 * MB_);
  u16*   h1nhi = (u16*)(ws + 27 * MB_);
  u16*   h1nlo = (u16*)(ws + 31 * MB_);
  float* h2g   = (float*)(ws + 35 * MB_);
  float* Eo    = (float*)(ws + 39 * MB_);
  float* To    = (float*)(ws + 39 * MB_ + 65536);
  float* Lo    = (float*)(ws + 39 * MB_ + 131072);
  double* slots = (double*)(ws + 39 * MB_ + 196608);

  prep_kernel<<<4256, 256, 0, stream>>>(pooled, ln1_g, ln1_b, W1, W2,
                                        xhi, xlo, w1thi, w1tlo, w2thi, w2tlo);
  // GEMM1: M=4096 N=512 K=1024, BM=64 tiles, grid 8*64=512, fused bias+GELU.
  gemm_gelu_kernel<64, 8, 64, 1024><<<512, 256, 0, stream>>>(
      xhi, xlo, w1thi, w1tlo, b1, h1g, nullptr);
  ln2_kernel<512, 2><<<4096, 256, 0, stream>>>(h1g, ln2_g, ln2_b, h1nhi, h1nlo);
  // GEMM2: M=4096 N=256 K=512, BM=32 tiles, grid 4*128=512, fused bias+GELU.
  gemm_gelu_kernel<32, 4, 128, 512><<<512, 256, 0, stream>>>(
      h1nhi, h1nlo, w2thi, w2tlo, b2, h2g, slots);
  head_kernel<<<1024, 256, 0, stream>>>(
      h2g, Wh, bh, labels, out + 1, To, Eo, Lo, slots);
  pairwise_kernel<<<2080, 256, 0, stream>>>(To, Eo, Lo, slots);
  finalize_kernel<<<1, 64, 0, stream>>>(slots, out);
}

// Round 11
// 203.544 us; speedup vs baseline: 1.4440x; 1.0480x over previous
//
#include <hip/hip_runtime.h>
#include <math.h>
#include <stdint.h>
#include <type_traits>

typedef unsigned short u16;
typedef unsigned long long u64;
typedef __attribute__((ext_vector_type(8))) short bf16x8;   // 8 bf16 (4 VGPRs)
typedef __attribute__((ext_vector_type(4))) float f32x4;

#define RSQRT1_2F 0.70710678118654752440f

// ---------------------------------------------------------------------------
// helpers
// ---------------------------------------------------------------------------
__device__ __forceinline__ u16 rne_bf16(float x) {
  unsigned u = __float_as_uint(x);
  return (u16)((u + 0x7FFFu + ((u >> 16) & 1u)) >> 16);
}
__device__ __forceinline__ float bf16_to_f(u16 h) {
  return __uint_as_float(((unsigned)h) << 16);
}
__device__ __forceinline__ void gload_lds16(const void* g, void* l) {
  __builtin_amdgcn_global_load_lds(
      (__attribute__((address_space(1))) void*)(uintptr_t)g,
      (__attribute__((address_space(3))) void*)(uintptr_t)l, 16, 0, 0);
}
__device__ __forceinline__ float rlane(float v, int sl) {
  return __uint_as_float((unsigned)__builtin_amdgcn_readlane((int)__float_as_uint(v), sl));
}
__device__ __forceinline__ float block_reduce_sum_f(float v, float* smem4) {
  #pragma unroll
  for (int off = 32; off > 0; off >>= 1) v += __shfl_down(v, off, 64);
  const int lane = threadIdx.x & 63;
  const int wid  = threadIdx.x >> 6;
  if (lane == 0) smem4[wid] = v;
  __syncthreads();
  float r = smem4[0] + smem4[1] + smem4[2] + smem4[3];
  __syncthreads();
  return r;
}
__device__ __forceinline__ float gelu_exact(float z) {
  return 0.5f * z * (1.0f + erff(z * RSQRT1_2F));
}

// ---------------------------------------------------------------------------
// prep bodies
// ---------------------------------------------------------------------------
template<int H, int NPT>
__device__ __forceinline__ void ln_split_body(
    const float* __restrict__ x, const float* __restrict__ g,
    const float* __restrict__ b, u16* __restrict__ yhi, u16* __restrict__ ylo,
    int row, float* smem4) {
  const float* xr = x + (size_t)row * H;
  const int tid = threadIdx.x;
  float v[NPT];
  #pragma unroll
  for (int q = 0; q < NPT; ++q) v[q] = xr[tid + q * 256];
  float s = 0.f;
  #pragma unroll
  for (int q = 0; q < NPT; ++q) s += v[q];
  s = block_reduce_sum_f(s, smem4);
  const float mu = s * (1.0f / H);
  float s2 = 0.f;
  #pragma unroll
  for (int q = 0; q < NPT; ++q) { float d = v[q] - mu; s2 = fmaf(d, d, s2); }
  s2 = block_reduce_sum_f(s2, smem4);
  const float rstd = rsqrtf(s2 * (1.0f / H) + 1e-5f);
  #pragma unroll
  for (int q = 0; q < NPT; ++q) {
    const int c = tid + q * 256;
    const float y = (v[q] - mu) * rstd * g[c] + b[c];
    const u16 h = rne_bf16(y);
    const u16 lo = rne_bf16(y - bf16_to_f(h));
    yhi[(size_t)row * H + c] = h;
    ylo[(size_t)row * H + c] = lo;
  }
}

template<int K, int N>
__device__ __forceinline__ void wsplit_body(
    const float* __restrict__ W, u16* __restrict__ Whi, u16* __restrict__ Wlo,
    int ntile, int ktile, float* sm /* 64*65 floats */) {
  const int t = threadIdx.x;
  const int n0 = ntile * 64, k0 = ktile * 64;
  #pragma unroll
  for (int q = 0; q < 16; ++q) {
    const int r = q * 4 + (t >> 6);
    sm[r * 65 + (t & 63)] = W[(size_t)(k0 + r) * N + n0 + (t & 63)];
  }
  __syncthreads();
  #pragma unroll
  for (int q = 0; q < 16; ++q) {
    const int nr = q * 4 + (t >> 6);
    const int kc = t & 63;
    const float v = sm[kc * 65 + nr];
    const u16 h = rne_bf16(v);
    const u16 lo = rne_bf16(v - bf16_to_f(h));
    Whi[(size_t)(n0 + nr) * K + k0 + kc] = h;
    Wlo[(size_t)(n0 + nr) * K + k0 + kc] = lo;
  }
}

// ---------------------------------------------------------------------------
// prep: blocks [0,4096) = LN1 rows; [4096,4224) = W1 tiles; [4224,4256) = W2.
// ---------------------------------------------------------------------------
__global__ __launch_bounds__(256) void prep_kernel(
    const float* __restrict__ pooled, const float* __restrict__ ln1_g,
    const float* __restrict__ ln1_b, const float* __restrict__ W1,
    const float* __restrict__ W2,
    u16* __restrict__ xhi, u16* __restrict__ xlo,
    u16* __restrict__ w1thi, u16* __restrict__ w1tlo,
    u16* __restrict__ w2thi, u16* __restrict__ w2tlo) {
  __shared__ float sm[64 * 65];
  const int bid = blockIdx.x;
  if (bid < 4096) {
    ln_split_body<1024, 4>(pooled, ln1_g, ln1_b, xhi, xlo, bid, sm);
  } else if (bid < 4224) {
    const int idx = bid - 4096;
    wsplit_body<1024, 512>(W1, w1thi, w1tlo, idx & 7, idx >> 3, sm);
  } else {
    const int idx = bid - 4224;
    wsplit_body<512, 256>(W2, w2thi, w2tlo, idx & 3, idx >> 2, sm);
  }
}

// ---------------------------------------------------------------------------
// bf16x3 split-MFMA GEMM, splitK=1, fused bias + exact GELU epilogue.
// Tile BM x 64, BK=32, double-buffered LDS, 2-phase pipeline.  Swizzle
// col ^= ((row>>1)&3)<<4.  Grid flat NX*MY, XCD-chunked bijective remap.
// zclr: block 0 zeroes the loss accumulator slots (544 doubles).
// ---------------------------------------------------------------------------
template<int BM, int NX, int MY, int K>
__global__ __launch_bounds__(256) void gemm_gelu_kernel(
    const u16* __restrict__ Ahi, const u16* __restrict__ Alo,
    const u16* __restrict__ Bhi, const u16* __restrict__ Blo,
    const float* __restrict__ bias, float* __restrict__ C, double* zclr) {
  constexpr int N  = NX * 64;
  constexpr int MF = BM / 32;             // M fragments per wave
  constexpr int ABYTES = BM * 64;         // one A half (hi or lo) per buffer
  constexpr int AOFF = 2 * ABYTES;        // B region offset
  constexpr int BUF  = AOFF + 8192;       // + B hi/lo (64 rows x 64 B x 2)
  constexpr int NS   = K / 32;
  __shared__ __align__(16) char sb[2 * BUF];

  if (zclr && blockIdx.x == 0) {
    const int t = threadIdx.x;
    zclr[t] = 0.0; zclr[t + 256] = 0.0;
    if (t < 32) zclr[t + 512] = 0.0;      // 544 doubles total
  }

  const int t = threadIdx.x, w = t >> 6, l = t & 63;
  const int lm = l & 15, lk = l >> 4;
  const int wm = w >> 1, wn = w & 1;
  int bid = (int)blockIdx.x;
  bid = (bid & 7) * ((NX * MY) >> 3) + (bid >> 3);   // XCD-chunked remap
  const int my = bid / NX, nx = bid % NX;
  const int m0 = my * BM, n0 = nx * 64;

  f32x4 acc[MF][2];
  #pragma unroll
  for (int m = 0; m < MF; ++m)
    #pragma unroll
    for (int n = 0; n < 2; ++n)
      #pragma unroll
      for (int r = 0; r < 4; ++r) acc[m][n][r] = 0.f;

  auto STAGE = [&](int bufsel, int k0) {
    char* bb = sb + bufsel * BUF;
    if constexpr (BM == 64) {
      const int row = t >> 2, cq = (t & 3) * 16;
      const int col = cq ^ (((row >> 1) & 3) << 4);
      const size_t gb = ((size_t)(m0 + row) * K + k0) * 2 + col;
      gload_lds16((const char*)Ahi + gb, bb + t * 16);
      gload_lds16((const char*)Alo + gb, bb + ABYTES + t * 16);
    } else {  // BM == 32
      const int half = t >> 7, tt = t & 127;
      const int row = tt >> 2, cq = (tt & 3) * 16;
      const int col = cq ^ (((row >> 1) & 3) << 4);
      const size_t gb = ((size_t)(m0 + row) * K + k0) * 2 + col;
      gload_lds16((const char*)(half ? Alo : Ahi) + gb,
                  bb + half * ABYTES + tt * 16);
    }
    {
      const int row = t >> 2, cq = (t & 3) * 16;
      const int col = cq ^ (((row >> 1) & 3) << 4);
      const size_t gb = ((size_t)(n0 + row) * K + k0) * 2 + col;
      gload_lds16((const char*)Bhi + gb, bb + AOFF + t * 16);
      gload_lds16((const char*)Blo + gb, bb + AOFF + 4096 + t * 16);
    }
  };
  auto COMPUTE = [&](int bufsel) {
    char* bb = sb + bufsel * BUF;
    bf16x8 ah[MF], al[MF], bhv[2], blv[2];
    #pragma unroll
    for (int m = 0; m < MF; ++m) {
      const int row = wm * (BM / 2) + m * 16 + lm;
      const int col = (lk * 16) ^ (((row >> 1) & 3) << 4);
      ah[m] = *(const bf16x8*)(bb + row * 64 + col);
      al[m] = *(const bf16x8*)(bb + ABYTES + row * 64 + col);
    }
    #pragma unroll
    for (int n = 0; n < 2; ++n) {
      const int row = wn * 32 + n * 16 + lm;
      const int col = (lk * 16) ^ (((row >> 1) & 3) << 4);
      bhv[n] = *(const bf16x8*)(bb + AOFF + row * 64 + col);
      blv[n] = *(const bf16x8*)(bb + AOFF + 4096 + row * 64 + col);
    }
    #pragma unroll
    for (int m = 0; m < MF; ++m)
      #pragma unroll
      for (int n = 0; n < 2; ++n) {
        acc[m][n] = __builtin_amdgcn_mfma_f32_16x16x32_bf16(ah[m], bhv[n], acc[m][n], 0, 0, 0);
        acc[m][n] = __builtin_amdgcn_mfma_f32_16x16x32_bf16(ah[m], blv[n], acc[m][n], 0, 0, 0);
        acc[m][n] = __builtin_amdgcn_mfma_f32_16x16x32_bf16(al[m], bhv[n], acc[m][n], 0, 0, 0);
      }
  };

  STAGE(0, 0);
  __syncthreads();
  for (int s = 0; s < NS; ++s) {
    if (s + 1 < NS) STAGE((s + 1) & 1, (s + 1) * 32);
    COMPUTE(s & 1);
    __syncthreads();
  }

  #pragma unroll
  for (int m = 0; m < MF; ++m)
    #pragma unroll
    for (int n = 0; n < 2; ++n) {
      const int col = n0 + wn * 32 + n * 16 + lm;
      const float bv = bias[col];
      #pragma unroll
      for (int r = 0; r < 4; ++r) {
        const int row = m0 + wm * (BM / 2) + m * 16 + lk * 4 + r;
        C[(size_t)row * N + col] = gelu_exact(acc[m][n][r] + bv);
      }
    }
}

// ---------------------------------------------------------------------------
// LN2: plain LayerNorm over h1g (gelu already applied by gemm1 epilogue).
// ---------------------------------------------------------------------------
template<int H, int NPT>
__global__ __launch_bounds__(256) void ln2_kernel(
    const float* __restrict__ x, const float* __restrict__ g,
    const float* __restrict__ b, u16* __restrict__ yhi, u16* __restrict__ ylo) {
  __shared__ float smem4[4];
  ln_split_body<H, NPT>(x, g, b, yhi, ylo, blockIdx.x, smem4);
}

// ---------------------------------------------------------------------------
// Head: z = h2g @ Wh + bh; p = sigmoid(z).  Emits logits, T=20*p,
// A=20*label, MSE into spread slots (E/L arrays no longer needed).
// ---------------------------------------------------------------------------
__global__ __launch_bounds__(256) void head_kernel(
    const float* __restrict__ h2g, const float* __restrict__ Wh,
    const float* __restrict__ bh, const float* __restrict__ labels,
    float* __restrict__ logits_out, float* __restrict__ To,
    float* __restrict__ Ao, double* __restrict__ mse_slots) {
  const int lane = threadIdx.x & 63;
  const int wv   = threadIdx.x >> 6;
  const int row  = blockIdx.x * 4 + wv;
  const size_t base = (size_t)row * 256;
  float a0 = 0.f, a1 = 0.f, a2 = 0.f, a3 = 0.f;
  #pragma unroll
  for (int q = 0; q < 4; ++q) {
    const int k = lane + q * 64;
    const float hv = h2g[base + k];
    const float4 wv4 = *(const float4*)&Wh[k * 4];
    a0 = fmaf(hv, wv4.x, a0); a1 = fmaf(hv, wv4.y, a1);
    a2 = fmaf(hv, wv4.z, a2); a3 = fmaf(hv, wv4.w, a3);
  }
  #pragma unroll
  for (int off = 32; off > 0; off >>= 1) {
    a0 += __shfl_down(a0, off, 64);
    a1 += __shfl_down(a1, off, 64);
    a2 += __shfl_down(a2, off, 64);
    a3 += __shfl_down(a3, off, 64);
  }
  if (lane == 0) {
    const float z[4] = {a0 + bh[0], a1 + bh[1], a2 + bh[2], a3 + bh[3]};
    float msew = 0.f;
    #pragma unroll
    for (int d = 0; d < 4; ++d) {
      const float p = 1.0f / (1.0f + expf(-z[d]));
      const float lab = labels[row * 4 + d];
      logits_out[row * 4 + d] = p;
      To[row * 4 + d] = 20.0f * p;
      Ao[row * 4 + d] = 20.0f * lab;
      const float df = p - lab;
      msew = fmaf(df, df, msew);
    }
    atomicAdd(&mse_slots[row & 31], (double)msew);
  }
}

// ---------------------------------------------------------------------------
// Pairwise ordering: one WAVE per full 64x64 upper-triangle tile (2080 waves,
// 520 blocks).  Softplus form — only 2 broadcast quantities per pair-dim:
//   u = Ti - Tj, v = Ai - Aj (A = 20*label)
//   bce = softplus(u) - sigmoid(v)*u
//   gate |li-lj|>0.01  <=>  |v| > 0.2
// cnt via ballot+popcount (scalar pipe).  256-slot spread atomics.
// Slots layout (doubles): [0..31] mse | [32..287] ord | [288..543] cnt(u64).
// ---------------------------------------------------------------------------
#define GFUN(t) ((t) * 64 - (t) * ((t) - 1) / 2)

__global__ __launch_bounds__(256) void pairwise_kernel(
    const float* __restrict__ To, const float* __restrict__ Ao,
    double* __restrict__ slots) {
  const int lane = threadIdx.x & 63;
  const int wv   = threadIdx.x >> 6;
  const int tile = blockIdx.x * 4 + wv;     // 0..2079

  int ti = (int)((129.0f - sqrtf(fmaxf(16641.0f - 8.0f * (float)tile, 0.f))) * 0.5f);
  if (ti < 0) ti = 0; if (ti > 63) ti = 63;
  while (ti > 0 && GFUN(ti) > tile) ti--;
  while (ti < 63 && GFUN(ti + 1) <= tile) ti++;
  const int tj = ti + (tile - GFUN(ti));
  const int i = ti * 64 + lane, j = tj * 64 + lane;

  const float4 t4 = *(const float4*)&To[(size_t)i * 4];
  const float4 a4 = *(const float4*)&Ao[(size_t)i * 4];
  const float Ti[4] = {t4.x, t4.y, t4.z, t4.w};
  const float Ai[4] = {a4.x, a4.y, a4.z, a4.w};
  const float4 tj4 = *(const float4*)&To[(size_t)j * 4];
  const float4 aj4 = *(const float4*)&Ao[(size_t)j * 4];
  const float Tjv[4] = {tj4.x, tj4.y, tj4.z, tj4.w};
  const float Ajv[4] = {aj4.x, aj4.y, aj4.z, aj4.w};

  float acc[4] = {0.f, 0.f, 0.f, 0.f};
  u64 cnt = 0;   // wave-uniform (ballot+popcount)

  auto body = [&](auto diagc) {
    constexpr bool DIAG = decltype(diagc)::value;
    #pragma unroll 8
    for (int s = 0; s < 64; ++s) {
      #pragma unroll
      for (int d = 0; d < 4; ++d) {
        const float Tj = rlane(Tjv[d], s);
        const float Aj = rlane(Ajv[d], s);
        const float u = Ti[d] - Tj;
        const float v = Ai[d] - Aj;
        const float sp = fmaxf(u, 0.f) + __logf(1.f + __expf(-fabsf(u)));
        const float sg = __builtin_amdgcn_rcpf(1.f + __expf(-v));
        const float bce = sp - sg * u;
        bool m = fabsf(v) > 0.2f;
        if constexpr (DIAG) m = m && (s > lane);
        acc[d] += m ? bce : 0.f;
        cnt += (u64)__popcll(__ballot(m));
      }
    }
  };
  if (ti == tj) body(std::integral_constant<bool, true>{});
  else          body(std::integral_constant<bool, false>{});

  float tot = (acc[0] + acc[1]) + (acc[2] + acc[3]);
  #pragma unroll
  for (int off = 32; off > 0; off >>= 1) tot += __shfl_down(tot, off, 64);
  if (lane == 0) {
    const int sl = tile & 255;
    atomicAdd(&slots[32 + sl], (double)tot);
    atomicAdd((u64*)(slots + 288) + sl, cnt);
  }
}

// ---------------------------------------------------------------------------
// finalize: reduce slot arrays, write the scalar loss.
// ---------------------------------------------------------------------------
__global__ void finalize_kernel(const double* __restrict__ slots,
                                float* __restrict__ out) {
  const int l = threadIdx.x;   // 64 threads
  double m = (l < 32) ? slots[l] : 0.0;
  double o = 0.0, c = 0.0;
  #pragma unroll
  for (int k = 0; k < 4; ++k) {
    o += slots[32 + l + k * 64];
    c += (double)((const u64*)(slots + 288))[l + k * 64];
  }
  #pragma unroll
  for (int off = 32; off > 0; off >>= 1) {
    m += __shfl_down(m, off, 64);
    o += __shfl_down(o, off, 64);
    c += __shfl_down(c, off, 64);
  }
  if (l == 0) {
    const double mse = m / (4096.0 * 4.0);
    const double ord = (c > 0.0) ? (o / c) : 0.0;
    out[0] = (float)(0.5 * mse + 0.5 * ord);
  }
}

// ---------------------------------------------------------------------------
extern "C" void kernel_launch(void* const* d_in, const int* in_sizes, int n_in,
                              void* d_out, int out_size, void* d_ws, size_t ws_size,
                              hipStream_t stream) {
  const float* pooled = (const float*)d_in[0];
  const float* labels = (const float*)d_in[1];
  const float* ln1_g  = (const float*)d_in[2];
  const float* ln1_b  = (const float*)d_in[3];
  const float* W1     = (const float*)d_in[4];
  const float* b1     = (const float*)d_in[5];
  const float* ln2_g  = (const float*)d_in[6];
  const float* ln2_b  = (const float*)d_in[7];
  const float* W2     = (const float*)d_in[8];
  const float* b2     = (const float*)d_in[9];
  const float* Wh     = (const float*)d_in[10];
  const float* bh     = (const float*)d_in[11];
  float* out = (float*)d_out;

  char* ws = (char*)d_ws;
  const size_t MB_ = 1048576;
  u16*   xhi   = (u16*)(ws + 0);
  u16*   xlo   = (u16*)(ws + 8 * MB_);
  u16*   w1thi = (u16*)(ws + 16 * MB_);
  u16*   w1tlo = (u16*)(ws + 17 * MB_);
  u16*   w2thi = (u16*)(ws + 18 * MB_);
  u16*   w2tlo = (u16*)(ws + 18 * MB_ + 262144);
  float* h1g   = (float*)(ws + 19 * MB_);
  u16*   h1nhi = (u16*)(ws + 27 * MB_);
  u16*   h1nlo = (u16*)(ws + 31 * MB_);
  float* h2g   = (float*)(ws + 35 * MB_);
  float* To    = (float*)(ws + 39 * MB_);
  float* Ao    = (float*)(ws + 39 * MB_ + 65536);
  double* slots = (double*)(ws + 39 * MB_ + 196608);  // 544 doubles

  prep_kernel<<<4256, 256, 0, stream>>>(pooled, ln1_g, ln1_b, W1, W2,
                                        xhi, xlo, w1thi, w1tlo, w2thi, w2tlo);
  gemm_gelu_kernel<64, 8, 64, 1024><<<512, 256, 0, stream>>>(
      xhi, xlo, w1thi, w1tlo, b1, h1g, nullptr);
  ln2_kernel<512, 2><<<4096, 256, 0, stream>>>(h1g, ln2_g, ln2_b, h1nhi, h1nlo);
  gemm_gelu_kernel<32, 4, 128, 512><<<512, 256, 0, stream>>>(
      h1nhi, h1nlo, w2thi, w2tlo, b2, h2g, slots);
  head_kernel<<<1024, 256, 0, stream>>>(
      h2g, Wh, bh, labels, out + 1, To, Ao, slots);
  pairwise_kernel<<<520, 256, 0, stream>>>(To, Ao, slots);
  finalize_kernel<<<1, 64, 0, stream>>>(slots, out);
}